// Round 6
// baseline (108.181 us; speedup 1.0000x reference)
//
#include <hip/hip_runtime.h>
#include <hip/hip_bf16.h>

typedef __attribute__((ext_vector_type(8))) short bf16x8;
typedef __attribute__((ext_vector_type(4))) float f32x4;
typedef __attribute__((ext_vector_type(4))) int i32x4;

#define BSZ   8192
#define DDIM  128
#define NCLS  512
#define SLOT  64                    // max members/class supported (actual max ~40)
#define NPAN  64                    // 128-row panels
#define NTRI  (NPAN * (NPAN + 1) / 2)   // 2080 upper-triangular 128x128 tiles
#define DGRID 256                   // persistent dense blocks, 1 per CU

#define L2E  1.44269504088896340736f
#define RLN2 0.69314718055994530942f

static __device__ __forceinline__ float fast_sqrt(float x) {
  float r; asm("v_sqrt_f32 %0, %1" : "=v"(r) : "v"(x)); return r;
}
static __device__ __forceinline__ float fast_exp2(float x) {
  float r; asm("v_exp_f32 %0, %1" : "=v"(r) : "v"(x)); return r;
}
static __device__ __forceinline__ float fast_log2(float x) {
  float r; asm("v_log_f32 %0, %1" : "=v"(r) : "v"(x)); return r;
}

static __device__ __forceinline__ void tile_ij(int t, int& bi, int& bj) {
  int j = (int)((sqrtf(8.0f * (float)t + 1.0f) - 1.0f) * 0.5f);
  while ((j + 1) * (j + 2) / 2 <= t) ++j;
  while (j * (j + 1) / 2 > t) --j;
  bi = t - j * (j + 1) / 2;
  bj = j;
}

// score -> bf16 copy + exact fp32 row magnitudes.
__global__ void prep_kernel(const float* __restrict__ score,
                            __hip_bfloat16* __restrict__ Sbf,
                            float* __restrict__ mag) {
  int gid = blockIdx.x * 256 + threadIdx.x;   // 131072 threads
  int row = gid >> 4, sub = gid & 15;
  const f32x4* src = (const f32x4*)(score + (size_t)row * DDIM + sub * 8);
  f32x4 a = src[0], b = src[1];
  union { ushort u[8]; i32x4 v; } pk;
  #pragma unroll
  for (int k = 0; k < 4; ++k) {
    __hip_bfloat16 ha = __float2bfloat16(a[k]);
    __hip_bfloat16 hb = __float2bfloat16(b[k]);
    pk.u[k] = *(const ushort*)&ha;
    pk.u[4 + k] = *(const ushort*)&hb;
  }
  *(i32x4*)((short*)Sbf + (size_t)row * DDIM + sub * 8) = pk.v;
  float sq = a[0]*a[0] + a[1]*a[1] + a[2]*a[2] + a[3]*a[3]
           + b[0]*b[0] + b[1]*b[1] + b[2]*b[2] + b[3]*b[3];
  sq += __shfl_xor(sq, 1); sq += __shfl_xor(sq, 2);
  sq += __shfl_xor(sq, 4); sq += __shfl_xor(sq, 8);
  if (sub == 0) mag[row] = sq;
}

// Persistent dense pass: 256 blocks x 512 threads; each block processes 8-9
// consecutive triangular 128x128 tiles with double-buffered LDS staging
// (global_load_lds, source-swizzled; conflict-free swizzled ds_read_b128).
// Cross-tile pipeline: ds_read cur -> issue stage(next) -> MFMA+epilogue ->
// barrier (drains stage) -> store partials -> barrier.
__launch_bounds__(512, 2)
__global__ void dense_pass(const __hip_bfloat16* __restrict__ Sbf,
                           const float* __restrict__ mag,
                           float* __restrict__ P,
                           int* __restrict__ ticket) {
  if (blockIdx.x == 0 && threadIdx.x == 0) *ticket = 0;  // for class_pass

  __shared__ char Abuf[2][128 * 256];          // 64 KB
  __shared__ char Bbuf[2][128 * 256];          // 64 KB
  __shared__ float Lrow[128][4];
  __shared__ float Lcol[128][2];

  const int tid = threadIdx.x;
  const int wid = tid >> 6, l = tid & 63;
  const int wr = wid >> 2, wc = wid & 3;       // 2x4 wave grid: 64x32 tiles
  const int lr = l >> 4, lc = l & 15;
  const short* S = (const short*)Sbf;

  const int b = blockIdx.x;
  const int cnt = 8 + (b < 32);                // 2080 = 256*8 + 32
  const int start = b * 8 + (b < 32 ? b : 32);

  // Stage tile t into buffer sel. Physical chunk p holds global chunk
  // (p&15)^((p>>4)&7) of row p>>4 (source-side swizzle, rule #21).
  auto stage = [&](int t, int sel) {
    int bi, bj; tile_ij(t, bi, bj);
    const size_t i0 = (size_t)bi * 128, j0 = (size_t)bj * 128;
    #pragma unroll
    for (int it = 0; it < 4; ++it) {
      int p = tid + it * 512;                  // 2048 chunks per tile
      int r = p >> 4;
      int g = (p & 15) ^ (r & 7);
      __builtin_amdgcn_global_load_lds(
          (const __attribute__((address_space(1))) void*)(S + (i0 + r) * DDIM + g * 8),
          (__attribute__((address_space(3))) void*)(Abuf[sel] + (wid * 64 + it * 512) * 16),
          16, 0, 0);
      __builtin_amdgcn_global_load_lds(
          (const __attribute__((address_space(1))) void*)(S + (j0 + r) * DDIM + g * 8),
          (__attribute__((address_space(3))) void*)(Bbuf[sel] + (wid * 64 + it * 512) * 16),
          16, 0, 0);
    }
  };

  stage(start, 0);
  __syncthreads();                             // drain prologue stage

  for (int k = 0; k < cnt; ++k) {
    const int cur = k & 1;
    const int t = start + k;
    int bi, bj; tile_ij(t, bi, bj);
    const int i0 = bi * 128, j0 = bj * 128;
    const bool diag = (bi == bj);

    // 1) ds_read all fragments for this tile into registers.
    bf16x8 af[4][4], bfr[4][2];
    #pragma unroll
    for (int ks = 0; ks < 4; ++ks) {
      const int c = ks * 4 + lr;
      #pragma unroll
      for (int m = 0; m < 4; ++m) {
        int r = wr * 64 + m * 16 + lc;
        af[ks][m] = *(const bf16x8*)(Abuf[cur] + r * 256 + ((c ^ (r & 7)) << 4));
      }
      #pragma unroll
      for (int n = 0; n < 2; ++n) {
        int r = wc * 32 + n * 16 + lc;
        bfr[ks][n] = *(const bf16x8*)(Bbuf[cur] + r * 256 + ((c ^ (r & 7)) << 4));
      }
    }

    // 2) issue next tile's stage; completes under compute, drained at barrier.
    if (k + 1 < cnt) stage(t + 1, cur ^ 1);

    // 3) mags + MFMA + epilogue
    float magj[2], magi[4][4];
    #pragma unroll
    for (int n = 0; n < 2; ++n) magj[n] = mag[j0 + wc * 32 + n * 16 + lc];
    #pragma unroll
    for (int m = 0; m < 4; ++m)
      #pragma unroll
      for (int rg = 0; rg < 4; ++rg)
        magi[m][rg] = mag[i0 + wr * 64 + m * 16 + lr * 4 + rg];

    f32x4 acc[4][2] = {};
    #pragma unroll
    for (int ks = 0; ks < 4; ++ks)
      #pragma unroll
      for (int m = 0; m < 4; ++m)
        #pragma unroll
        for (int n = 0; n < 2; ++n)
          acc[m][n] = __builtin_amdgcn_mfma_f32_16x16x32_bf16(
              af[ks][m], bfr[ks][n], acc[m][n], 0, 0, 0);

    float rs[4][4] = {};
    float cs[2] = {};
    #pragma unroll
    for (int m = 0; m < 4; ++m)
      #pragma unroll
      for (int n = 0; n < 2; ++n)
        #pragma unroll
        for (int rg = 0; rg < 4; ++rg) {
          // C layout: col = lane&15, row = (lane>>4)*4 + reg
          float d2 = fmaxf(magi[m][rg] + magj[n] - 2.0f * acc[m][n][rg], 0.0f);
          float e = fast_exp2((1.0f - fast_sqrt(d2)) * L2E);
          if (diag) {
            int rrow = wr * 64 + m * 16 + lr * 4 + rg;
            int ccol = wc * 32 + n * 16 + lc;
            if (rrow == ccol) e = 0.0f;        // exclude i == j
          }
          rs[m][rg] += e;
          cs[n] += e;
        }

    // 4) cross-lane reductions -> LDS
    #pragma unroll
    for (int m = 0; m < 4; ++m)
      #pragma unroll
      for (int rg = 0; rg < 4; ++rg) {
        float v = rs[m][rg];
        v += __shfl_xor(v, 1); v += __shfl_xor(v, 2);
        v += __shfl_xor(v, 4); v += __shfl_xor(v, 8);
        if (lc == 0) Lrow[wr * 64 + m * 16 + lr * 4 + rg][wc] = v;
      }
    if (!diag) {
      #pragma unroll
      for (int n = 0; n < 2; ++n) {
        float v = cs[n];
        v += __shfl_xor(v, 16); v += __shfl_xor(v, 32);
        if (lr == 0) Lcol[wc * 32 + n * 16 + lc][wr] = v;
      }
    }
    __syncthreads();   // Lrow/Lcol ready; drains stage(k+1) (vmcnt(0))
    float* Pt = P + (size_t)t * 256;
    if (tid < 128)
      Pt[tid] = Lrow[tid][0] + Lrow[tid][1] + Lrow[tid][2] + Lrow[tid][3];
    else if (tid < 256 && !diag)
      Pt[tid] = Lcol[tid - 128][0] + Lcol[tid - 128][1];
    __syncthreads();   // Lrow/Lcol reusable next tile
  }
}

// Per-class pass: wave-0 scans targets (deterministic ballot compaction),
// gathers Nfull from tile partials, exact fp32 pairwise distances among
// members, per-class partial loss/cnt; last block reduces and writes out.
__launch_bounds__(256)
__global__ void class_pass(const float* __restrict__ score,
                           const float* __restrict__ mag,
                           const float* __restrict__ P,
                           const int* __restrict__ targets,
                           float* __restrict__ partial,
                           int* __restrict__ ticket,
                           float* __restrict__ out) {
  const int c = blockIdx.x;
  const int tid = threadIdx.x;
  __shared__ int mem[SLOT];
  __shared__ int nShared;
  __shared__ int lastFlag;
  __shared__ float rows[SLOT][132];   // [.][128] holds mag
  __shared__ float Nf[SLOT];
  __shared__ float Ns[SLOT];
  __shared__ float dmat[SLOT * SLOT];
  __shared__ float redL[4], redC[4];

  // member discovery: wave 0, index-ordered ballot compaction
  if (tid < 64) {
    int base = 0;
    for (int rd = 0; rd < BSZ / 64; ++rd) {
      int idx = rd * 64 + tid;
      bool m = (targets[idx] == c);
      unsigned long long bm = __ballot(m);
      if (m) {
        int pos = base + __popcll(bm & ((1ull << tid) - 1ull));
        if (pos < SLOT) mem[pos] = idx;
      }
      base += __popcll(bm);
    }
    if (tid == 0) nShared = base < SLOT ? base : SLOT;
  }
  __syncthreads();
  const int n = nShared;

  float ll = 0.0f, lcn = 0.0f;
  if (n >= 2) {
    for (int i = tid; i < n; i += 256) { Ns[i] = 0.0f; Nf[i] = 0.0f; }
    __syncthreads();
    for (int w = tid; w < n * 32; w += 256) {
      int i = w >> 5, ch = w & 31;
      *(f32x4*)&rows[i][ch * 4] = *(const f32x4*)(score + (size_t)mem[i] * DDIM + ch * 4);
    }
    for (int i = tid; i < n; i += 256) rows[i][128] = mag[mem[i]];
    // gather Nfull from the 64 panel partials per member
    for (int w = tid; w < n * 64; w += 256) {
      int i = w >> 6, q = w & 63;
      int gi = mem[i], pp = gi >> 7, off = gi & 127;
      float v = (q >= pp) ? P[(size_t)(q * (q + 1) / 2 + pp) * 256 + off]
                          : P[(size_t)(pp * (pp + 1) / 2 + q) * 256 + 128 + off];
      atomicAdd(&Nf[i], v);
    }
    __syncthreads();
    const int np = n * n;
    for (int p = tid; p < np; p += 256) {
      int i = p / n, j = p - i * n;
      float dd = 0.0f;
      if (i != j) {
        float dot = 0.0f;
        #pragma unroll
        for (int k = 0; k < 32; ++k) {
          f32x4 a = *(const f32x4*)&rows[i][k * 4];
          f32x4 b = *(const f32x4*)&rows[j][k * 4];
          dot += a[0]*b[0] + a[1]*b[1] + a[2]*b[2] + a[3]*b[3];
        }
        float d2 = fmaxf(rows[i][128] + rows[j][128] - 2.0f * dot, 0.0f);
        dd = fast_sqrt(d2);
        atomicAdd(&Ns[i], fast_exp2((1.0f - dd) * L2E));
      }
      dmat[p] = dd;
    }
    __syncthreads();
    for (int i = tid; i < n; i += 256) Nf[i] -= Ns[i];
    __syncthreads();
    for (int p = tid; p < np; p += 256) {
      int i = p / n, j = p - i * n;
      if (i == j) continue;
      float ln = fast_log2(Nf[i] + Nf[j]) * RLN2 + dmat[p];
      if (ln > 0.0f) ll += ln * ln;
      lcn += 1.0f;
    }
  }
  #pragma unroll
  for (int m = 1; m < 64; m <<= 1) {
    ll  += __shfl_xor(ll, m);
    lcn += __shfl_xor(lcn, m);
  }
  if ((tid & 63) == 0) { redL[tid >> 6] = ll; redC[tid >> 6] = lcn; }
  __syncthreads();
  if (tid == 0) {
    partial[2 * c]     = redL[0] + redL[1] + redL[2] + redL[3];
    partial[2 * c + 1] = redC[0] + redC[1] + redC[2] + redC[3];
    __threadfence();
    lastFlag = (atomicAdd(ticket, 1) == NCLS - 1);
  }
  __syncthreads();
  if (lastFlag) {
    float sl = 0.0f, sc = 0.0f;
    for (int i = tid; i < NCLS; i += 256) {
      sl += atomicAdd(&partial[2 * i], 0.0f);       // device-scope reads
      sc += atomicAdd(&partial[2 * i + 1], 0.0f);
    }
    #pragma unroll
    for (int m = 1; m < 64; m <<= 1) {
      sl += __shfl_xor(sl, m);
      sc += __shfl_xor(sc, m);
    }
    if ((tid & 63) == 0) { redL[tid >> 6] = sl; redC[tid >> 6] = sc; }
    __syncthreads();
    if (tid == 0) {
      float L = redL[0] + redL[1] + redL[2] + redL[3];
      float C = redC[0] + redC[1] + redC[2] + redC[3];
      out[0] = L / (4.0f * C);
    }
  }
}

extern "C" void kernel_launch(void* const* d_in, const int* in_sizes, int n_in,
                              void* d_out, int out_size, void* d_ws, size_t ws_size,
                              hipStream_t stream) {
  const float* score = (const float*)d_in[0];
  const int* targets = (const int*)d_in[1];
  float* out = (float*)d_out;

  char* ws = (char*)d_ws;
  size_t cur = 0;
  auto alloc = [&](size_t bytes) -> void* {
    void* p = ws + cur;
    cur += (bytes + 255) & ~(size_t)255;
    return p;
  };
  __hip_bfloat16* Sbf = (__hip_bfloat16*)alloc((size_t)BSZ * DDIM * 2);
  float* mag     = (float*)alloc(BSZ * 4);
  float* P       = (float*)alloc((size_t)NTRI * 256 * 4);
  float* partial = (float*)alloc(NCLS * 2 * 4);
  int*   ticket  = (int*)alloc(4);

  prep_kernel<<<BSZ * 16 / 256, 256, 0, stream>>>(score, Sbf, mag);
  dense_pass<<<DGRID, 512, 0, stream>>>(Sbf, mag, P, ticket);
  class_pass<<<NCLS, 256, 0, stream>>>(score, mag, P, targets,
                                       partial, ticket, out);
}

// Round 7
// 83.538 us; speedup vs baseline: 1.2950x; 1.2950x over previous
//
#include <hip/hip_runtime.h>
#include <hip/hip_bf16.h>

typedef __attribute__((ext_vector_type(8))) short bf16x8;
typedef __attribute__((ext_vector_type(4))) float f32x4;
typedef __attribute__((ext_vector_type(4))) int i32x4;

#define BSZ   8192
#define DDIM  128
#define NCLS  512
#define SLOT  64                    // max members/class supported (actual max ~40)
#define NPAN  64                    // 128-row panels
#define NTRI  (NPAN * (NPAN + 1) / 2)   // 2080 upper-triangular 128x128 tiles
#define DGRID 256                   // persistent dense blocks, 1 per CU

#define L2E  1.44269504088896340736f
#define RLN2 0.69314718055994530942f

static __device__ __forceinline__ float fast_sqrt(float x) {
  float r; asm("v_sqrt_f32 %0, %1" : "=v"(r) : "v"(x)); return r;
}
static __device__ __forceinline__ float fast_exp2(float x) {
  float r; asm("v_exp_f32 %0, %1" : "=v"(r) : "v"(x)); return r;
}
static __device__ __forceinline__ float fast_log2(float x) {
  float r; asm("v_log_f32 %0, %1" : "=v"(r) : "v"(x)); return r;
}

static __device__ __forceinline__ void tile_ij(int t, int& bi, int& bj) {
  int j = (int)((sqrtf(8.0f * (float)t + 1.0f) - 1.0f) * 0.5f);
  while ((j + 1) * (j + 2) / 2 <= t) ++j;
  while (j * (j + 1) / 2 > t) --j;
  bi = t - j * (j + 1) / 2;
  bj = j;
}

// score -> bf16 copy + exact fp32 row magnitudes.
__global__ void prep_kernel(const float* __restrict__ score,
                            __hip_bfloat16* __restrict__ Sbf,
                            float* __restrict__ mag) {
  int gid = blockIdx.x * 256 + threadIdx.x;   // 131072 threads
  int row = gid >> 4, sub = gid & 15;
  const f32x4* src = (const f32x4*)(score + (size_t)row * DDIM + sub * 8);
  f32x4 a = src[0], b = src[1];
  union { ushort u[8]; i32x4 v; } pk;
  #pragma unroll
  for (int k = 0; k < 4; ++k) {
    __hip_bfloat16 ha = __float2bfloat16(a[k]);
    __hip_bfloat16 hb = __float2bfloat16(b[k]);
    pk.u[k] = *(const ushort*)&ha;
    pk.u[4 + k] = *(const ushort*)&hb;
  }
  *(i32x4*)((short*)Sbf + (size_t)row * DDIM + sub * 8) = pk.v;
  float sq = a[0]*a[0] + a[1]*a[1] + a[2]*a[2] + a[3]*a[3]
           + b[0]*b[0] + b[1]*b[1] + b[2]*b[2] + b[3]*b[3];
  sq += __shfl_xor(sq, 1); sq += __shfl_xor(sq, 2);
  sq += __shfl_xor(sq, 4); sq += __shfl_xor(sq, 8);
  if (sub == 0) mag[row] = sq;
}

// Persistent dense pass: 256 blocks x 512 threads; each block processes 8-9
// consecutive triangular 128x128 tiles with double-buffered LDS staging
// (global_load_lds, source-swizzled; conflict-free swizzled ds_read_b128).
// Cross-tile pipeline: ds_read cur -> issue stage(next) -> MFMA+epilogue ->
// barrier (drains stage) -> store partials -> barrier.
__launch_bounds__(512, 2)
__global__ void dense_pass(const __hip_bfloat16* __restrict__ Sbf,
                           const float* __restrict__ mag,
                           float* __restrict__ P,
                           int* __restrict__ ticket) {
  if (blockIdx.x == 0 && threadIdx.x == 0) *ticket = 0;  // for class_pass

  __shared__ char Abuf[2][128 * 256];          // 64 KB
  __shared__ char Bbuf[2][128 * 256];          // 64 KB
  __shared__ float Lrow[128][4];
  __shared__ float Lcol[128][2];

  const int tid = threadIdx.x;
  const int wid = tid >> 6, l = tid & 63;
  const int wr = wid >> 2, wc = wid & 3;       // 2x4 wave grid: 64x32 tiles
  const int lr = l >> 4, lc = l & 15;
  const short* S = (const short*)Sbf;

  const int b = blockIdx.x;
  const int cnt = 8 + (b < 32);                // 2080 = 256*8 + 32
  const int start = b * 8 + (b < 32 ? b : 32);

  // Stage tile t into buffer sel. Physical chunk p holds global chunk
  // (p&15)^((p>>4)&7) of row p>>4 (source-side swizzle, rule #21).
  auto stage = [&](int t, int sel) {
    int bi, bj; tile_ij(t, bi, bj);
    const size_t i0 = (size_t)bi * 128, j0 = (size_t)bj * 128;
    #pragma unroll
    for (int it = 0; it < 4; ++it) {
      int p = tid + it * 512;                  // 2048 chunks per tile
      int r = p >> 4;
      int g = (p & 15) ^ (r & 7);
      __builtin_amdgcn_global_load_lds(
          (const __attribute__((address_space(1))) void*)(S + (i0 + r) * DDIM + g * 8),
          (__attribute__((address_space(3))) void*)(Abuf[sel] + (wid * 64 + it * 512) * 16),
          16, 0, 0);
      __builtin_amdgcn_global_load_lds(
          (const __attribute__((address_space(1))) void*)(S + (j0 + r) * DDIM + g * 8),
          (__attribute__((address_space(3))) void*)(Bbuf[sel] + (wid * 64 + it * 512) * 16),
          16, 0, 0);
    }
  };

  stage(start, 0);
  __syncthreads();                             // drain prologue stage

  for (int k = 0; k < cnt; ++k) {
    const int cur = k & 1;
    const int t = start + k;
    int bi, bj; tile_ij(t, bi, bj);
    const int i0 = bi * 128, j0 = bj * 128;
    const bool diag = (bi == bj);

    // 1) ds_read all fragments for this tile into registers.
    bf16x8 af[4][4], bfr[4][2];
    #pragma unroll
    for (int ks = 0; ks < 4; ++ks) {
      const int c = ks * 4 + lr;
      #pragma unroll
      for (int m = 0; m < 4; ++m) {
        int r = wr * 64 + m * 16 + lc;
        af[ks][m] = *(const bf16x8*)(Abuf[cur] + r * 256 + ((c ^ (r & 7)) << 4));
      }
      #pragma unroll
      for (int n = 0; n < 2; ++n) {
        int r = wc * 32 + n * 16 + lc;
        bfr[ks][n] = *(const bf16x8*)(Bbuf[cur] + r * 256 + ((c ^ (r & 7)) << 4));
      }
    }

    // 2) issue next tile's stage; completes under compute, drained at barrier.
    if (k + 1 < cnt) stage(t + 1, cur ^ 1);

    // 3) mags + MFMA + epilogue
    float magj[2], magi[4][4];
    #pragma unroll
    for (int n = 0; n < 2; ++n) magj[n] = mag[j0 + wc * 32 + n * 16 + lc];
    #pragma unroll
    for (int m = 0; m < 4; ++m)
      #pragma unroll
      for (int rg = 0; rg < 4; ++rg)
        magi[m][rg] = mag[i0 + wr * 64 + m * 16 + lr * 4 + rg];

    f32x4 acc[4][2] = {};
    #pragma unroll
    for (int ks = 0; ks < 4; ++ks)
      #pragma unroll
      for (int m = 0; m < 4; ++m)
        #pragma unroll
        for (int n = 0; n < 2; ++n)
          acc[m][n] = __builtin_amdgcn_mfma_f32_16x16x32_bf16(
              af[ks][m], bfr[ks][n], acc[m][n], 0, 0, 0);

    float rs[4][4] = {};
    float cs[2] = {};
    #pragma unroll
    for (int m = 0; m < 4; ++m)
      #pragma unroll
      for (int n = 0; n < 2; ++n)
        #pragma unroll
        for (int rg = 0; rg < 4; ++rg) {
          // C layout: col = lane&15, row = (lane>>4)*4 + reg
          float d2 = fmaxf(magi[m][rg] + magj[n] - 2.0f * acc[m][n][rg], 0.0f);
          float e = fast_exp2((1.0f - fast_sqrt(d2)) * L2E);
          if (diag) {
            int rrow = wr * 64 + m * 16 + lr * 4 + rg;
            int ccol = wc * 32 + n * 16 + lc;
            if (rrow == ccol) e = 0.0f;        // exclude i == j
          }
          rs[m][rg] += e;
          cs[n] += e;
        }

    // 4) cross-lane reductions -> LDS
    #pragma unroll
    for (int m = 0; m < 4; ++m)
      #pragma unroll
      for (int rg = 0; rg < 4; ++rg) {
        float v = rs[m][rg];
        v += __shfl_xor(v, 1); v += __shfl_xor(v, 2);
        v += __shfl_xor(v, 4); v += __shfl_xor(v, 8);
        if (lc == 0) Lrow[wr * 64 + m * 16 + lr * 4 + rg][wc] = v;
      }
    if (!diag) {
      #pragma unroll
      for (int n = 0; n < 2; ++n) {
        float v = cs[n];
        v += __shfl_xor(v, 16); v += __shfl_xor(v, 32);
        if (lr == 0) Lcol[wc * 32 + n * 16 + lc][wr] = v;
      }
    }
    __syncthreads();   // Lrow/Lcol ready; drains stage(k+1) (vmcnt(0))
    float* Pt = P + (size_t)t * 256;
    if (tid < 128)
      Pt[tid] = Lrow[tid][0] + Lrow[tid][1] + Lrow[tid][2] + Lrow[tid][3];
    else if (tid < 256 && !diag)
      Pt[tid] = Lcol[tid - 128][0] + Lcol[tid - 128][1];
    __syncthreads();   // Lrow/Lcol reusable next tile
  }
}

// Per-class pass: parallel member discovery (LDS atomic append; pair-sum is
// order-insensitive), gather Nfull from tile partials, exact fp32 pairwise
// distances among members, per-class partial loss/cnt; last block reduces
// and writes out.
__launch_bounds__(256)
__global__ void class_pass(const float* __restrict__ score,
                           const float* __restrict__ mag,
                           const float* __restrict__ P,
                           const int* __restrict__ targets,
                           float* __restrict__ partial,
                           int* __restrict__ ticket,
                           float* __restrict__ out) {
  const int c = blockIdx.x;
  const int tid = threadIdx.x;
  __shared__ int mem[SLOT];
  __shared__ int nCnt;
  __shared__ int lastFlag;
  __shared__ float rows[SLOT][132];   // [.][128] holds mag
  __shared__ float Nf[SLOT];
  __shared__ float Ns[SLOT];
  __shared__ float dmat[SLOT * SLOT];
  __shared__ float redL[4], redC[4];

  if (tid == 0) nCnt = 0;
  __syncthreads();
  // parallel member discovery: coalesced scan + LDS atomic append
  #pragma unroll
  for (int rd = 0; rd < BSZ / 256; ++rd) {
    int idx = rd * 256 + tid;
    if (targets[idx] == c) {
      int p = atomicAdd(&nCnt, 1);
      if (p < SLOT) mem[p] = idx;
    }
  }
  __syncthreads();
  const int n = nCnt < SLOT ? nCnt : SLOT;

  float ll = 0.0f, lcn = 0.0f;
  if (n >= 2) {
    for (int i = tid; i < n; i += 256) { Ns[i] = 0.0f; Nf[i] = 0.0f; }
    __syncthreads();
    for (int w = tid; w < n * 32; w += 256) {
      int i = w >> 5, ch = w & 31;
      *(f32x4*)&rows[i][ch * 4] = *(const f32x4*)(score + (size_t)mem[i] * DDIM + ch * 4);
    }
    for (int i = tid; i < n; i += 256) rows[i][128] = mag[mem[i]];
    // gather Nfull from the 64 panel partials per member
    for (int w = tid; w < n * 64; w += 256) {
      int i = w >> 6, q = w & 63;
      int gi = mem[i], pp = gi >> 7, off = gi & 127;
      float v = (q >= pp) ? P[(size_t)(q * (q + 1) / 2 + pp) * 256 + off]
                          : P[(size_t)(pp * (pp + 1) / 2 + q) * 256 + 128 + off];
      atomicAdd(&Nf[i], v);
    }
    __syncthreads();
    const int np = n * n;
    for (int p = tid; p < np; p += 256) {
      int i = p / n, j = p - i * n;
      float dd = 0.0f;
      if (i != j) {
        float dot = 0.0f;
        #pragma unroll
        for (int k = 0; k < 32; ++k) {
          f32x4 a = *(const f32x4*)&rows[i][k * 4];
          f32x4 b = *(const f32x4*)&rows[j][k * 4];
          dot += a[0]*b[0] + a[1]*b[1] + a[2]*b[2] + a[3]*b[3];
        }
        float d2 = fmaxf(rows[i][128] + rows[j][128] - 2.0f * dot, 0.0f);
        dd = fast_sqrt(d2);
        atomicAdd(&Ns[i], fast_exp2((1.0f - dd) * L2E));
      }
      dmat[p] = dd;
    }
    __syncthreads();
    for (int i = tid; i < n; i += 256) Nf[i] -= Ns[i];
    __syncthreads();
    for (int p = tid; p < np; p += 256) {
      int i = p / n, j = p - i * n;
      if (i == j) continue;
      float ln = fast_log2(Nf[i] + Nf[j]) * RLN2 + dmat[p];
      if (ln > 0.0f) ll += ln * ln;
      lcn += 1.0f;
    }
  }
  #pragma unroll
  for (int m = 1; m < 64; m <<= 1) {
    ll  += __shfl_xor(ll, m);
    lcn += __shfl_xor(lcn, m);
  }
  if ((tid & 63) == 0) { redL[tid >> 6] = ll; redC[tid >> 6] = lcn; }
  __syncthreads();
  if (tid == 0) {
    partial[2 * c]     = redL[0] + redL[1] + redL[2] + redL[3];
    partial[2 * c + 1] = redC[0] + redC[1] + redC[2] + redC[3];
    __threadfence();
    lastFlag = (atomicAdd(ticket, 1) == NCLS - 1);
  }
  __syncthreads();
  if (lastFlag) {
    float sl = 0.0f, sc = 0.0f;
    for (int i = tid; i < NCLS; i += 256) {
      sl += atomicAdd(&partial[2 * i], 0.0f);       // device-scope reads
      sc += atomicAdd(&partial[2 * i + 1], 0.0f);
    }
    #pragma unroll
    for (int m = 1; m < 64; m <<= 1) {
      sl += __shfl_xor(sl, m);
      sc += __shfl_xor(sc, m);
    }
    if ((tid & 63) == 0) { redL[tid >> 6] = sl; redC[tid >> 6] = sc; }
    __syncthreads();
    if (tid == 0) {
      float L = redL[0] + redL[1] + redL[2] + redL[3];
      float C = redC[0] + redC[1] + redC[2] + redC[3];
      out[0] = L / (4.0f * C);
    }
  }
}

extern "C" void kernel_launch(void* const* d_in, const int* in_sizes, int n_in,
                              void* d_out, int out_size, void* d_ws, size_t ws_size,
                              hipStream_t stream) {
  const float* score = (const float*)d_in[0];
  const int* targets = (const int*)d_in[1];
  float* out = (float*)d_out;

  char* ws = (char*)d_ws;
  size_t cur = 0;
  auto alloc = [&](size_t bytes) -> void* {
    void* p = ws + cur;
    cur += (bytes + 255) & ~(size_t)255;
    return p;
  };
  __hip_bfloat16* Sbf = (__hip_bfloat16*)alloc((size_t)BSZ * DDIM * 2);
  float* mag     = (float*)alloc(BSZ * 4);
  float* P       = (float*)alloc((size_t)NTRI * 256 * 4);
  float* partial = (float*)alloc(NCLS * 2 * 4);
  int*   ticket  = (int*)alloc(4);

  prep_kernel<<<BSZ * 16 / 256, 256, 0, stream>>>(score, Sbf, mag);
  dense_pass<<<DGRID, 512, 0, stream>>>(Sbf, mag, P, ticket);
  class_pass<<<NCLS, 256, 0, stream>>>(score, mag, P, targets,
                                       partial, ticket, out);
}

// Round 8
// 63.509 us; speedup vs baseline: 1.7034x; 1.3154x over previous
//
#include <hip/hip_runtime.h>
#include <hip/hip_bf16.h>

typedef __attribute__((ext_vector_type(8))) short bf16x8;
typedef __attribute__((ext_vector_type(4))) float f32x4;
typedef __attribute__((ext_vector_type(4))) int i32x4;

#define BSZ   8192
#define DDIM  128
#define NCLS  512
#define SLOT  64                    // max members/class supported (actual max ~40)
#define NPAN  64                    // 128-row panels
#define NTRI  (NPAN * (NPAN + 1) / 2)   // 2080 upper-triangular 128x128 tiles

#define L2E  1.44269504088896340736f
#define RLN2 0.69314718055994530942f

static __device__ __forceinline__ float fast_sqrt(float x) {
  float r; asm("v_sqrt_f32 %0, %1" : "=v"(r) : "v"(x)); return r;
}
static __device__ __forceinline__ float fast_exp2(float x) {
  float r; asm("v_exp_f32 %0, %1" : "=v"(r) : "v"(x)); return r;
}
static __device__ __forceinline__ float fast_log2(float x) {
  float r; asm("v_log_f32 %0, %1" : "=v"(r) : "v"(x)); return r;
}

static __device__ __forceinline__ void tile_ij(int t, int& bi, int& bj) {
  int j = (int)((sqrtf(8.0f * (float)t + 1.0f) - 1.0f) * 0.5f);
  while ((j + 1) * (j + 2) / 2 <= t) ++j;
  while (j * (j + 1) / 2 > t) --j;
  bi = t - j * (j + 1) / 2;
  bj = j;
}

// score -> bf16 in MFMA-FRAGMENT order + exact fp32 row magnitudes.
// 16B chunk (row, c) [c = col-chunk 0..15 = ks*4+lr] lives at chunk index
// ((row>>4)*4 + (c>>2))*64 + (c&3)*16 + (row&15)  -- so a wave reading
// fragment (rowblock, ks) reads 64 consecutive 16B chunks (1 KB coalesced).
__global__ void prep_kernel(const float* __restrict__ score,
                            __hip_bfloat16* __restrict__ Sfrag,
                            float* __restrict__ mag) {
  int gid = blockIdx.x * 256 + threadIdx.x;   // 131072 threads
  int row = gid >> 4, sub = gid & 15;
  const f32x4* src = (const f32x4*)(score + (size_t)row * DDIM + sub * 8);
  f32x4 a = src[0], b = src[1];
  union { ushort u[8]; i32x4 v; } pk;
  #pragma unroll
  for (int k = 0; k < 4; ++k) {
    __hip_bfloat16 ha = __float2bfloat16(a[k]);
    __hip_bfloat16 hb = __float2bfloat16(b[k]);
    pk.u[k] = *(const ushort*)&ha;
    pk.u[4 + k] = *(const ushort*)&hb;
  }
  size_t chunk = ((size_t)(row >> 4) * 4 + (sub >> 2)) * 64
               + (size_t)(sub & 3) * 16 + (row & 15);
  ((i32x4*)Sfrag)[chunk] = pk.v;
  float sq = a[0]*a[0] + a[1]*a[1] + a[2]*a[2] + a[3]*a[3]
           + b[0]*b[0] + b[1]*b[1] + b[2]*b[2] + b[3]*b[3];
  sq += __shfl_xor(sq, 1); sq += __shfl_xor(sq, 2);
  sq += __shfl_xor(sq, 4); sq += __shfl_xor(sq, 8);
  if (sub == 0) mag[row] = sq;
}

// Dense symmetric pass: one 512-thread block (2x4 waves of 64x32) per
// upper-triangular 128x128 tile. NO staging LDS: fragments are loaded as
// fully-coalesced 1KB global loads from the fragment-ordered bf16 array
// (L2-resident). No barriers until the tiny partial-sum combine at the end.
__launch_bounds__(512, 4)
__global__ void dense_pass(const __hip_bfloat16* __restrict__ Sfrag,
                           const float* __restrict__ mag,
                           float* __restrict__ P,
                           int* __restrict__ ticket) {
  if (blockIdx.x == 0 && threadIdx.x == 0) *ticket = 0;  // for class_pass

  const int t = blockIdx.x;
  int bi, bj; tile_ij(t, bi, bj);
  const int i0 = bi * 128, j0 = bj * 128;
  const bool diag = (bi == bj);

  __shared__ float Lrow[128][4];
  __shared__ float Lcol[128][2];

  const int tid = threadIdx.x;
  const int wid = tid >> 6, l = tid & 63;
  const int wr = wid >> 2, wc = wid & 3;       // 2x4 wave grid: 64x32 tiles
  const int lr = l >> 4, lc = l & 15;

  const bf16x8* F = (const bf16x8*)Sfrag;      // one bf16x8 = one 16B chunk
  const int pa = (i0 >> 4) + wr * 4;           // A panel16 base
  const int pb = (j0 >> 4) + wc * 2;           // B panel16 base

  f32x4 acc[4][2] = {};
  #pragma unroll
  for (int ks = 0; ks < 4; ++ks) {
    bf16x8 af[4], bfr[2];
    #pragma unroll
    for (int m = 0; m < 4; ++m)
      af[m] = F[(size_t)((pa + m) * 4 + ks) * 64 + l];
    #pragma unroll
    for (int n = 0; n < 2; ++n)
      bfr[n] = F[(size_t)((pb + n) * 4 + ks) * 64 + l];
    #pragma unroll
    for (int m = 0; m < 4; ++m)
      #pragma unroll
      for (int n = 0; n < 2; ++n)
        acc[m][n] = __builtin_amdgcn_mfma_f32_16x16x32_bf16(
            af[m], bfr[n], acc[m][n], 0, 0, 0);
  }

  float magj[2], magi[4][4];
  #pragma unroll
  for (int n = 0; n < 2; ++n) magj[n] = mag[j0 + wc * 32 + n * 16 + lc];
  #pragma unroll
  for (int m = 0; m < 4; ++m)
    #pragma unroll
    for (int rg = 0; rg < 4; ++rg)
      magi[m][rg] = mag[i0 + wr * 64 + m * 16 + lr * 4 + rg];

  float rs[4][4] = {};
  float cs[2] = {};
  #pragma unroll
  for (int m = 0; m < 4; ++m)
    #pragma unroll
    for (int n = 0; n < 2; ++n)
      #pragma unroll
      for (int rg = 0; rg < 4; ++rg) {
        // C layout: col = lane&15, row = (lane>>4)*4 + reg
        float d2 = fmaxf(magi[m][rg] + magj[n] - 2.0f * acc[m][n][rg], 0.0f);
        float e = fast_exp2((1.0f - fast_sqrt(d2)) * L2E);
        if (diag) {
          int rrow = wr * 64 + m * 16 + lr * 4 + rg;
          int ccol = wc * 32 + n * 16 + lc;
          if (rrow == ccol) e = 0.0f;          // exclude i == j
        }
        rs[m][rg] += e;
        cs[n] += e;
      }

  // cross-lane reductions -> LDS
  #pragma unroll
  for (int m = 0; m < 4; ++m)
    #pragma unroll
    for (int rg = 0; rg < 4; ++rg) {
      float v = rs[m][rg];
      v += __shfl_xor(v, 1); v += __shfl_xor(v, 2);
      v += __shfl_xor(v, 4); v += __shfl_xor(v, 8);
      if (lc == 0) Lrow[wr * 64 + m * 16 + lr * 4 + rg][wc] = v;
    }
  if (!diag) {
    #pragma unroll
    for (int n = 0; n < 2; ++n) {
      float v = cs[n];
      v += __shfl_xor(v, 16); v += __shfl_xor(v, 32);
      if (lr == 0) Lcol[wc * 32 + n * 16 + lc][wr] = v;
    }
  }
  __syncthreads();
  float* Pt = P + (size_t)t * 256;
  if (tid < 128)
    Pt[tid] = Lrow[tid][0] + Lrow[tid][1] + Lrow[tid][2] + Lrow[tid][3];
  else if (tid < 256 && !diag)
    Pt[tid] = Lcol[tid - 128][0] + Lcol[tid - 128][1];
}

// Per-class pass: parallel member discovery (LDS atomic append; pair-sum is
// order-insensitive), gather Nfull from tile partials, exact fp32 pairwise
// distances among members, per-class partial loss/cnt; last block reduces
// and writes out.
__launch_bounds__(256)
__global__ void class_pass(const float* __restrict__ score,
                           const float* __restrict__ mag,
                           const float* __restrict__ P,
                           const int* __restrict__ targets,
                           float* __restrict__ partial,
                           int* __restrict__ ticket,
                           float* __restrict__ out) {
  const int c = blockIdx.x;
  const int tid = threadIdx.x;
  __shared__ int mem[SLOT];
  __shared__ int nCnt;
  __shared__ int lastFlag;
  __shared__ float rows[SLOT][132];   // [.][128] holds mag
  __shared__ float Nf[SLOT];
  __shared__ float Ns[SLOT];
  __shared__ float dmat[SLOT * SLOT];
  __shared__ float redL[4], redC[4];

  if (tid == 0) nCnt = 0;
  __syncthreads();
  // parallel member discovery: coalesced scan + LDS atomic append
  #pragma unroll
  for (int rd = 0; rd < BSZ / 256; ++rd) {
    int idx = rd * 256 + tid;
    if (targets[idx] == c) {
      int p = atomicAdd(&nCnt, 1);
      if (p < SLOT) mem[p] = idx;
    }
  }
  __syncthreads();
  const int n = nCnt < SLOT ? nCnt : SLOT;

  float ll = 0.0f, lcn = 0.0f;
  if (n >= 2) {
    for (int i = tid; i < n; i += 256) { Ns[i] = 0.0f; Nf[i] = 0.0f; }
    __syncthreads();
    for (int w = tid; w < n * 32; w += 256) {
      int i = w >> 5, ch = w & 31;
      *(f32x4*)&rows[i][ch * 4] = *(const f32x4*)(score + (size_t)mem[i] * DDIM + ch * 4);
    }
    for (int i = tid; i < n; i += 256) rows[i][128] = mag[mem[i]];
    // gather Nfull from the 64 panel partials per member
    for (int w = tid; w < n * 64; w += 256) {
      int i = w >> 6, q = w & 63;
      int gi = mem[i], pp = gi >> 7, off = gi & 127;
      float v = (q >= pp) ? P[(size_t)(q * (q + 1) / 2 + pp) * 256 + off]
                          : P[(size_t)(pp * (pp + 1) / 2 + q) * 256 + 128 + off];
      atomicAdd(&Nf[i], v);
    }
    __syncthreads();
    const int np = n * n;
    for (int p = tid; p < np; p += 256) {
      int i = p / n, j = p - i * n;
      float dd = 0.0f;
      if (i != j) {
        float dot = 0.0f;
        #pragma unroll
        for (int k = 0; k < 32; ++k) {
          f32x4 a = *(const f32x4*)&rows[i][k * 4];
          f32x4 b = *(const f32x4*)&rows[j][k * 4];
          dot += a[0]*b[0] + a[1]*b[1] + a[2]*b[2] + a[3]*b[3];
        }
        float d2 = fmaxf(rows[i][128] + rows[j][128] - 2.0f * dot, 0.0f);
        dd = fast_sqrt(d2);
        atomicAdd(&Ns[i], fast_exp2((1.0f - dd) * L2E));
      }
      dmat[p] = dd;
    }
    __syncthreads();
    for (int i = tid; i < n; i += 256) Nf[i] -= Ns[i];
    __syncthreads();
    for (int p = tid; p < np; p += 256) {
      int i = p / n, j = p - i * n;
      if (i == j) continue;
      float ln = fast_log2(Nf[i] + Nf[j]) * RLN2 + dmat[p];
      if (ln > 0.0f) ll += ln * ln;
      lcn += 1.0f;
    }
  }
  #pragma unroll
  for (int m = 1; m < 64; m <<= 1) {
    ll  += __shfl_xor(ll, m);
    lcn += __shfl_xor(lcn, m);
  }
  if ((tid & 63) == 0) { redL[tid >> 6] = ll; redC[tid >> 6] = lcn; }
  __syncthreads();
  if (tid == 0) {
    partial[2 * c]     = redL[0] + redL[1] + redL[2] + redL[3];
    partial[2 * c + 1] = redC[0] + redC[1] + redC[2] + redC[3];
    __threadfence();
    lastFlag = (atomicAdd(ticket, 1) == NCLS - 1);
  }
  __syncthreads();
  if (lastFlag) {
    float sl = 0.0f, sc = 0.0f;
    for (int i = tid; i < NCLS; i += 256) {
      sl += atomicAdd(&partial[2 * i], 0.0f);       // device-scope reads
      sc += atomicAdd(&partial[2 * i + 1], 0.0f);
    }
    #pragma unroll
    for (int m = 1; m < 64; m <<= 1) {
      sl += __shfl_xor(sl, m);
      sc += __shfl_xor(sc, m);
    }
    if ((tid & 63) == 0) { redL[tid >> 6] = sl; redC[tid >> 6] = sc; }
    __syncthreads();
    if (tid == 0) {
      float L = redL[0] + redL[1] + redL[2] + redL[3];
      float C = redC[0] + redC[1] + redC[2] + redC[3];
      out[0] = L / (4.0f * C);
    }
  }
}

extern "C" void kernel_launch(void* const* d_in, const int* in_sizes, int n_in,
                              void* d_out, int out_size, void* d_ws, size_t ws_size,
                              hipStream_t stream) {
  const float* score = (const float*)d_in[0];
  const int* targets = (const int*)d_in[1];
  float* out = (float*)d_out;

  char* ws = (char*)d_ws;
  size_t cur = 0;
  auto alloc = [&](size_t bytes) -> void* {
    void* p = ws + cur;
    cur += (bytes + 255) & ~(size_t)255;
    return p;
  };
  __hip_bfloat16* Sfrag = (__hip_bfloat16*)alloc((size_t)BSZ * DDIM * 2);
  float* mag     = (float*)alloc(BSZ * 4);
  float* P       = (float*)alloc((size_t)NTRI * 256 * 4);
  float* partial = (float*)alloc(NCLS * 2 * 4);
  int*   ticket  = (int*)alloc(4);

  prep_kernel<<<BSZ * 16 / 256, 256, 0, stream>>>(score, Sfrag, mag);
  dense_pass<<<NTRI, 512, 0, stream>>>(Sfrag, mag, P, ticket);
  class_pass<<<NCLS, 256, 0, stream>>>(score, mag, P, targets,
                                       partial, ticket, out);
}